// Round 12
// baseline (5717.170 us; speedup 1.0000x reference)
//
#include <hip/hip_runtime.h>
#include <hip/hip_cooperative_groups.h>
#include <math.h>

namespace cg = cooperative_groups;

#define HD    1024
#define BATCH 4096
#define VOC   64
#define MSGL  16
#define KH    1024   // GEMM K = hidden only (x-half folded into XG table)
#define NG    4096   // gates width = 4H

typedef _Float16 f16;
typedef _Float16 f16x8 __attribute__((ext_vector_type(8)));
typedef _Float16 f16x4 __attribute__((ext_vector_type(4)));
typedef float    f32x4 __attribute__((ext_vector_type(4)));

__device__ __forceinline__ void splt(float v, f16& hi, f16& lo) {
    f16 h = (f16)v;
    hi = h;
    lo = (f16)(v - (float)h);
}

// fast sigmoid/tanh via v_exp_f32 (2^x) + v_rcp_f32; error ~3e-7
__device__ __forceinline__ float sigm_f(float x) {
    return __builtin_amdgcn_rcpf(1.0f + __builtin_amdgcn_exp2f(-1.44269504088896f * x));
}
__device__ __forceinline__ float tanh_f(float x) {
    return 1.0f - 2.0f * __builtin_amdgcn_rcpf(1.0f + __builtin_amdgcn_exp2f(2.88539008177793f * x));
}

// permuted gate index (256-col tiles):
//   n' = bxx*256 + jh*64 + g*16 + cn   (bxx=n'>>8, jh 0..3, g 0..3, cn 0..15)
//   j  = bxx*64 + jh*16 + cn,  orig n = g*1024 + j
__device__ __forceinline__ int orig_n(int np) {
    const int bxx = np >> 8, rem = np & 255;
    const int jh = rem >> 6, g = (rem >> 4) & 3, cnn = rem & 15;
    return g * 1024 + bxx * 64 + jh * 16 + cnn;
}
__device__ __forceinline__ int j_of(int np) {
    const int bxx = np >> 8, rem = np & 255;
    const int jh = rem >> 6, cnn = rem & 15;
    return bxx * 64 + jh * 16 + cnn;
}

__device__ __forceinline__ void async16(void* lds, const void* g) {
    __builtin_amdgcn_global_load_lds(
        (const __attribute__((address_space(1))) void*)g,
        (__attribute__((address_space(3))) void*)lds, 16, 0, 0);
}

// swizzled byte offset in a [256-row][128B-row] LDS tile; granule = 16B unit 0..7
// (r4/r7-proven layout)
__device__ __forceinline__ int swz(int row, int gran) {
    return row * 128 + ((gran ^ (row & 7)) << 4);
}

// stage one 8KB round of a [256][128B] tile: linear LDS dest (gload_lds
// requirement), inverse-swizzled global source. granules 0..3 = hi k-octets,
// 4..7 = lo. (r4/r7-proven staging function)
__device__ __forceinline__ void stage(char* ldsbase, const f16* hi, const f16* lo,
                                      int gbase, int k0, int r, int tid) {
    const int o   = (r * 512 + tid) * 16;
    const int row = o >> 7;
    const int gp  = (o >> 4) & 7;
    const int g   = gp ^ (row & 7);
    const f16* src = (g < 4 ? hi : lo) + (size_t)(gbase + row) * KH + k0 + (g & 3) * 8;
    async16(ldsbase + o, src);
}

// ---------------- persistent fused decoder loop ------------------------------
// 256 blocks x 512 threads, cooperative. Per step t:
//   GEMM phase (r9-verified): 256x256 tile, 8 waves, counted vmcnt(4) x2,
//     fused XG gather + fast-math LSTM cell, writes cbuf + next h (hi/lo).
//   grid.sync
//   logits phase: block d owns rows 16d..16d+15 (8 waves x 2 rows),
//     softmax/argmax/outputs/ambuf.
//   grid.sync
__global__ __launch_bounds__(512, 1) void fused_loop(
    f16* __restrict__ Hh0, f16* __restrict__ Hl0,
    f16* __restrict__ Hh1, f16* __restrict__ Hl1,
    const f16* __restrict__ Whi, const f16* __restrict__ Wlo,
    const float* __restrict__ XG, int* __restrict__ ambuf,
    float* __restrict__ cbuf,
    const float* __restrict__ W_outT, const float* __restrict__ b_out,
    float* __restrict__ omsg0, float* __restrict__ odig0,
    float* __restrict__ ologp)
{
    cg::grid_group grid = cg::this_grid();
    __shared__ char smem[132096];   // K-loop: 2 x [A 32K|B 32K]; epilogue overlay
    __shared__ int sAm[256];

    const int tid  = threadIdx.x;
    const int lane = tid & 63;
    const int wv   = tid >> 6;          // 0..7
    const int wm   = wv >> 2;           // 0..1 (128-row half)
    const int wn   = wv & 3;            // 0..3 (64-col quarter)
    const int d    = blockIdx.x;        // 0..255
    const int by   = d >> 4;            // 0..15
    const int bx   = d & 15;            // 0..15
    const int bm   = by * 256;          // batch rows
    const int bnp  = bx * 256;          // permuted gate cols
    const int rl   = lane & 15;
    const int kg   = lane >> 4;         // k-octet 0..3

#pragma unroll 1
    for (int t = 0; t < MSGL; ++t) {
        const f16* Hh = (t & 1) ? Hh1 : Hh0;
        const f16* Hl = (t & 1) ? Hl1 : Hl0;
        f16* HhN = (t & 1) ? Hh0 : Hh1;
        f16* HlN = (t & 1) ? Hl0 : Hl1;

        // ================= GEMM phase (r9 body) =================
        f32x4 acc[8][4];
#pragma unroll
        for (int i = 0; i < 8; ++i)
#pragma unroll
            for (int g = 0; g < 4; ++g) acc[i][g] = f32x4{0.f, 0.f, 0.f, 0.f};

        if (tid < 256) sAm[tid] = (t == 0) ? 64 : ambuf[bm + tid];

        // prologue: stage tile 0 into buf0 (A-pair first, then B-pair)
#pragma unroll
        for (int r = 0; r < 4; ++r) stage(smem,         Hh,  Hl,  bm,  0, r, tid);
#pragma unroll
        for (int r = 0; r < 4; ++r) stage(smem + 32768, Whi, Wlo, bnp, 0, r, tid);

        for (int kt = 0; kt < 32; ++kt) {
            const char* cb = smem + (kt & 1) * 65536;
            char* nb = smem + ((kt + 1) & 1) * 65536;
            const int kn = ((kt + 1) & 31) * 32;    // wrap at last tile (junk into dead buf)

            // top: A-units of this tile must be ready; prev B-units may fly
            asm volatile("s_waitcnt vmcnt(4)" ::: "memory");
            asm volatile("s_barrier" ::: "memory");

            // stage next tile's A-pair (4 loads/thread)
#pragma unroll
            for (int r = 0; r < 4; ++r) stage(nb, Hh, Hl, bm, kn, r, tid);

            // mid: B-units of this tile must be ready; my new A-stages may fly
            asm volatile("s_waitcnt vmcnt(4)" ::: "memory");
            asm volatile("s_barrier" ::: "memory");

            f16x8 bh[4], bl[4];
#pragma unroll
            for (int f = 0; f < 4; ++f) {
                const int row = wn * 64 + f * 16 + rl;
                bh[f] = *(const f16x8*)(cb + 32768 + swz(row, kg));
                bl[f] = *(const f16x8*)(cb + 32768 + swz(row, kg + 4));
            }
            // stage next tile's B-pair
#pragma unroll
            for (int r = 0; r < 4; ++r) stage(nb + 32768, Whi, Wlo, bnp, kn, r, tid);

            __builtin_amdgcn_s_setprio(1);
#pragma unroll
            for (int f = 0; f < 8; ++f) {
                const int row = wm * 128 + f * 16 + rl;
                const f16x8 ah = *(const f16x8*)(cb + swz(row, kg));
                const f16x8 al = *(const f16x8*)(cb + swz(row, kg + 4));
#pragma unroll
                for (int g = 0; g < 4; ++g) {
                    acc[f][g] = __builtin_amdgcn_mfma_f32_16x16x32_f16(ah, bh[g], acc[f][g], 0, 0, 0);
                    acc[f][g] = __builtin_amdgcn_mfma_f32_16x16x32_f16(ah, bl[g], acc[f][g], 0, 0, 0);
                    acc[f][g] = __builtin_amdgcn_mfma_f32_16x16x32_f16(al, bh[g], acc[f][g], 0, 0, 0);
                }
            }
            __builtin_amdgcn_s_setprio(0);
        }

        // drain junk prefetch before reusing LDS
        asm volatile("s_waitcnt vmcnt(0)" ::: "memory");
        __syncthreads();

        // ---- epilogue: XG slice -> LDS (coalesced), fast cell, h via LDS ----
        float* sXG = (float*)smem;                  // [65][256] f32 (66.5 KB)
        f16*   hHi = (f16*)(smem + 66560);          // [256][64] (32 KB)
        f16*   hLo = (f16*)(smem + 99328);          // [256][64] (32 KB)
        const int jb = bx * 64;                     // j column base

#pragma unroll
        for (int i = 0; i < 9; ++i) {
            const int idx = i * 512 + tid;          // float4 units; need 65*64=4160
            if (idx < 65 * 64) {
                const int v  = idx >> 6;
                const int c4 = (idx & 63) * 4;
                *(float4*)&sXG[v * 256 + c4] =
                    *(const float4*)&XG[(size_t)v * NG + bnp + c4];
            }
        }
        __syncthreads();

        const int q    = lane >> 4;
        const int lcol = wn * 16 + rl;
        const int jglob = jb + lcol;
#pragma unroll
        for (int i = 0; i < 8; ++i) {
#pragma unroll
            for (int rg = 0; rg < 4; ++rg) {
                const int lrow = wm * 128 + i * 16 + q * 4 + rg;
                const int v = sAm[lrow];
                const float4 xg = *(const float4*)&sXG[v * 256 + lcol * 4];
                const size_t ci = (size_t)(bm + lrow) * HD + jglob;
                const float cold = cbuf[ci];
                const float I = sigm_f(acc[i][0][rg] + xg.x);
                const float F = sigm_f(acc[i][1][rg] + xg.y);
                const float G = tanh_f(acc[i][2][rg] + xg.z);
                const float O = sigm_f(acc[i][3][rg] + xg.w);
                const float cc = F * cold + I * G;
                const float hh = O * tanh_f(cc);
                cbuf[ci] = cc;
                f16 hi_, lo_;
                splt(hh, hi_, lo_);
                hHi[lrow * 64 + lcol] = hi_;
                hLo[lrow * 64 + lcol] = lo_;
            }
        }
        __syncthreads();

        // coalesced h write-out
#pragma unroll
        for (int r = 0; r < 8; ++r) {
            const int idx = r * 512 + tid;
            const int row = idx >> 4;
            const int c4  = (idx & 15) * 4;
            *(f16x4*)&HhN[(size_t)(bm + row) * HD + jb + c4] = *(f16x4*)&hHi[row * 64 + c4];
            *(f16x4*)&HlN[(size_t)(bm + row) * HD + jb + c4] = *(f16x4*)&hLo[row * 64 + c4];
        }

        __threadfence();
        grid.sync();

        // ================= logits phase =================
        {
            float* omsg = omsg0 + (size_t)t * BATCH * VOC;
            float* odig = odig0 + (size_t)t * BATCH * VOC;
            const int r0 = d * 16 + wv * 2;

            float a0 = 0.f, a1 = 0.f;
            const f16* hh0 = HhN + (size_t)r0 * HD;
            const f16* hl0 = HlN + (size_t)r0 * HD;
            const f16* hh1 = hh0 + HD;
            const f16* hl1 = hl0 + HD;
            for (int k = 0; k < HD; k += 4) {
                const float w0 = W_outT[(k + 0) * 64 + lane];
                const float w1 = W_outT[(k + 1) * 64 + lane];
                const float w2 = W_outT[(k + 2) * 64 + lane];
                const float w3 = W_outT[(k + 3) * 64 + lane];
                const f16x4 vh0 = *(const f16x4*)&hh0[k];
                const f16x4 vl0 = *(const f16x4*)&hl0[k];
                const f16x4 vh1 = *(const f16x4*)&hh1[k];
                const f16x4 vl1 = *(const f16x4*)&hl1[k];
                a0 += w0 * ((float)vh0[0] + (float)vl0[0]) + w1 * ((float)vh0[1] + (float)vl0[1])
                    + w2 * ((float)vh0[2] + (float)vl0[2]) + w3 * ((float)vh0[3] + (float)vl0[3]);
                a1 += w0 * ((float)vh1[0] + (float)vl1[0]) + w1 * ((float)vh1[1] + (float)vl1[1])
                    + w2 * ((float)vh1[2] + (float)vl1[2]) + w3 * ((float)vh1[3] + (float)vl1[3]);
            }
            const float bo = b_out[lane];
            const float accs[2] = {a0, a1};

#pragma unroll
            for (int r = 0; r < 2; ++r) {
                const int row = r0 + r;
                const float lg = accs[r] + bo;

                float m = lg; int am = lane;
#pragma unroll
                for (int dd = 1; dd < 64; dd <<= 1) {
                    const float om = __shfl_xor(m, dd);
                    const int   oa = __shfl_xor(am, dd);
                    if (om > m || (om == m && oa < am)) { m = om; am = oa; }
                }
                float s = expf(lg - m);
#pragma unroll
                for (int dd = 1; dd < 64; dd <<= 1) s += __shfl_xor(s, dd);

                odig[(size_t)row * VOC + lane] = lg;
                omsg[(size_t)row * VOC + lane] = (lane == am) ? 1.0f : 0.0f;
                if (lane == 0) {
                    const float prev = (t == 0) ? 0.0f : ologp[row];
                    ologp[row] = prev - logf(s);   // log(probs[argmax]) = -log(sum exp(l-m))
                    ambuf[row] = am;
                }
            }
        }

        __threadfence();
        grid.sync();
    }
}

// ---------------- XG table: XG[v][j*4+g] = relu(x_v)@W_ih^T + b_ih + b_hh ---
// one wave per n'; lane == v (0..63); lane 0 also writes the t=0 row (v=64).
__global__ __launch_bounds__(256) void xg_kernel(
    const float* __restrict__ W_ih, const float* __restrict__ rembT,  // [1024][64]
    const float* __restrict__ rembX0, const float* __restrict__ bR,
    float* __restrict__ XG)                                           // [65][4096]
{
    __shared__ float sW[4][1024];
    const int lane = threadIdx.x & 63;
    const int wv   = threadIdx.x >> 6;
    const int np   = blockIdx.x * 4 + wv;
    const int orig = orig_n(np);
    const float* wr = W_ih + (size_t)orig * HD;
#pragma unroll
    for (int c = 0; c < 4; ++c)
        *(float4*)&sW[wv][c * 256 + lane * 4] = *(const float4*)&wr[c * 256 + lane * 4];
    __syncthreads();

    float acc = 0.f, acc0 = 0.f;
#pragma unroll 4
    for (int k = 0; k < HD; ++k) {
        const float w = sW[wv][k];
        acc  += w * rembT[k * 64 + lane];
        acc0 += w * rembX0[k];
    }
    const float b = bR[np];
    const int g = (np >> 4) & 3;
    const int pos = j_of(np) * 4 + g;
    XG[(size_t)lane * NG + pos] = acc + b;
    if (lane == 0) XG[(size_t)64 * NG + pos] = acc0 + b;
}

// ---------------- prep kernels ----------------------------------------------
__global__ __launch_bounds__(256) void prep_w(
    const float* __restrict__ W_hh, f16* __restrict__ Whi, f16* __restrict__ Wlo)
{
    const long long idx = ((long long)blockIdx.x * 256 + threadIdx.x) * 4; // NG*KH
    const int np = (int)(idx >> 10);
    const int k  = (int)(idx & 1023);
    const float4 v = *(const float4*)&W_hh[(size_t)orig_n(np) * HD + k];
    f16x4 vh, vl; f16 hi_, lo_;
    splt(v.x, hi_, lo_); vh[0] = hi_; vl[0] = lo_;
    splt(v.y, hi_, lo_); vh[1] = hi_; vl[1] = lo_;
    splt(v.z, hi_, lo_); vh[2] = hi_; vl[2] = lo_;
    splt(v.w, hi_, lo_); vh[3] = hi_; vl[3] = lo_;
    *(f16x4*)&Whi[idx] = vh;
    *(f16x4*)&Wlo[idx] = vl;
}

__global__ __launch_bounds__(256) void prep_h(
    const float* __restrict__ ench, f16* __restrict__ Hh, f16* __restrict__ Hl)
{
    const int idx = (blockIdx.x * 256 + threadIdx.x) * 4;   // BATCH*HD
    const float4 v = *(const float4*)&ench[idx];
    f16x4 vh, vl; f16 hi_, lo_;
    splt(v.x, hi_, lo_); vh[0] = hi_; vl[0] = lo_;
    splt(v.y, hi_, lo_); vh[1] = hi_; vl[1] = lo_;
    splt(v.z, hi_, lo_); vh[2] = hi_; vl[2] = lo_;
    splt(v.w, hi_, lo_); vh[3] = hi_; vl[3] = lo_;
    *(f16x4*)&Hh[idx] = vh;
    *(f16x4*)&Hl[idx] = vl;
}

__global__ __launch_bounds__(256) void prep_c(
    const float* __restrict__ encc, float* __restrict__ cbuf)
{
    const int idx = (blockIdx.x * 256 + threadIdx.x) * 4;
    *(float4*)&cbuf[idx] = *(const float4*)&encc[idx];
}

// mask, W_out transpose, relu(emb) transpose, relu(x0), bias reorder
__global__ __launch_bounds__(256) void prep_small(
    const float* __restrict__ W_out, const float* __restrict__ b_ih,
    const float* __restrict__ b_hh, const float* __restrict__ emb,
    const float* __restrict__ x0,
    float* __restrict__ W_outT, float* __restrict__ rembT,
    float* __restrict__ rembX0, float* __restrict__ bR, float* __restrict__ mask)
{
    const int i = blockIdx.x * 256 + threadIdx.x;   // 0..65535
    mask[i] = 1.0f;
    const int v = i >> 10, k = i & 1023;
    W_outT[k * 64 + v] = W_out[i];
    rembT[k * 64 + v] = fmaxf(emb[i], 0.f);
    if (i < 1024) rembX0[i] = fmaxf(x0[i], 0.f);
    if (i < NG) {
        const int orig = orig_n(i);
        bR[i] = b_ih[orig] + b_hh[orig];
    }
}

// ---------------- launch ----------------------------------------------------
extern "C" void kernel_launch(void* const* d_in, const int* in_sizes, int n_in,
                              void* d_out, int out_size, void* d_ws, size_t ws_size,
                              hipStream_t stream)
{
    const float* ench  = (const float*)d_in[0];
    const float* encc  = (const float*)d_in[1];
    const float* W_ih  = (const float*)d_in[2];
    const float* W_hh  = (const float*)d_in[3];
    const float* b_ih  = (const float*)d_in[4];
    const float* b_hh  = (const float*)d_in[5];
    const float* W_out = (const float*)d_in[6];
    const float* b_out = (const float*)d_in[7];
    const float* x0    = (const float*)d_in[8];
    const float* emb   = (const float*)d_in[9];
    float* out = (float*)d_out;

    char* ws = (char*)d_ws;
    f16*   Hh0    = (f16*)(ws + ((size_t) 0 << 20));
    f16*   Hl0    = (f16*)(ws + ((size_t) 8 << 20));
    f16*   Hh1    = (f16*)(ws + ((size_t)16 << 20));
    f16*   Hl1    = (f16*)(ws + ((size_t)24 << 20));
    f16*   Whr    = (f16*)(ws + ((size_t)32 << 20));
    f16*   Wlr    = (f16*)(ws + ((size_t)40 << 20));
    float* cbuf   = (float*)(ws + ((size_t)48 << 20));
    float* W_outT = (float*)(ws + ((size_t)64 << 20));
    float* rembT  = (float*)(ws + ((size_t)65 << 20));
    float* rembX0 = (float*)(ws + ((size_t)66 << 20));
    float* bR     = (float*)(ws + ((size_t)66 << 20) + 8192);
    float* XG     = (float*)(ws + ((size_t)67 << 20));
    int*   ambuf  = (int*)  (ws + ((size_t)69 << 20));

    float* out_msg0 = out;                                        // [L,B,V]
    float* out_mask = out + (size_t)MSGL * BATCH * VOC;           // [L,1,B]
    float* out_dig0 = out_mask + (size_t)MSGL * BATCH;            // [L,B,V]
    float* out_logp = out_dig0 + (size_t)MSGL * BATCH * VOC;      // [B]

    prep_w<<<4096, 256, 0, stream>>>(W_hh, Whr, Wlr);
    prep_h<<<4096, 256, 0, stream>>>(ench, Hh0, Hl0);
    prep_c<<<4096, 256, 0, stream>>>(encc, cbuf);
    prep_small<<<256, 256, 0, stream>>>(W_out, b_ih, b_hh, emb, x0,
                                        W_outT, rembT, rembX0, bR, out_mask);
    xg_kernel<<<1024, 256, 0, stream>>>(W_ih, rembT, rembX0, bR, XG);

    void* kargs[] = {
        (void*)&Hh0, (void*)&Hl0, (void*)&Hh1, (void*)&Hl1,
        (void*)&Whr, (void*)&Wlr, (void*)&XG, (void*)&ambuf,
        (void*)&cbuf, (void*)&W_outT, (void*)&b_out,
        (void*)&out_msg0, (void*)&out_dig0, (void*)&out_logp
    };
    hipLaunchCooperativeKernel((void*)fused_loop, dim3(256), dim3(512),
                               kargs, 0, stream);
}

// Round 13
// 1945.835 us; speedup vs baseline: 2.9382x; 2.9382x over previous
//
#include <hip/hip_runtime.h>
#include <math.h>

#define HD    1024
#define BATCH 4096
#define VOC   64
#define MSGL  16
#define KH    1024   // GEMM K = hidden only (x-half folded into XG table)
#define NG    4096   // gates width = 4H

typedef _Float16 f16;
typedef _Float16 f16x8 __attribute__((ext_vector_type(8)));
typedef _Float16 f16x4 __attribute__((ext_vector_type(4)));
typedef float    f32x4 __attribute__((ext_vector_type(4)));

__device__ __forceinline__ void splt(float v, f16& hi, f16& lo) {
    f16 h = (f16)v;
    hi = h;
    lo = (f16)(v - (float)h);
}

// fast sigmoid/tanh via v_exp_f32 (2^x) + v_rcp_f32; error ~3e-7
__device__ __forceinline__ float sigm_f(float x) {
    return __builtin_amdgcn_rcpf(1.0f + __builtin_amdgcn_exp2f(-1.44269504088896f * x));
}
__device__ __forceinline__ float tanh_f(float x) {
    return 1.0f - 2.0f * __builtin_amdgcn_rcpf(1.0f + __builtin_amdgcn_exp2f(2.88539008177793f * x));
}

// permuted gate index (256-col tiles):
//   n' = bxx*256 + jh*64 + g*16 + cn   (bxx=n'>>8, jh 0..3, g 0..3, cn 0..15)
//   j  = bxx*64 + jh*16 + cn,  orig n = g*1024 + j
__device__ __forceinline__ int orig_n(int np) {
    const int bxx = np >> 8, rem = np & 255;
    const int jh = rem >> 6, g = (rem >> 4) & 3, cnn = rem & 15;
    return g * 1024 + bxx * 64 + jh * 16 + cnn;
}
__device__ __forceinline__ int j_of(int np) {
    const int bxx = np >> 8, rem = np & 255;
    const int jh = rem >> 6, cnn = rem & 15;
    return bxx * 64 + jh * 16 + cnn;
}

__device__ __forceinline__ void async16(void* lds, const void* g) {
    __builtin_amdgcn_global_load_lds(
        (const __attribute__((address_space(1))) void*)g,
        (__attribute__((address_space(3))) void*)lds, 16, 0, 0);
}

// swizzled byte offset in a [rows][128B-row] LDS tile; granule = 16B unit 0..7
// (r4/r7-proven layout)
__device__ __forceinline__ int swz(int row, int gran) {
    return row * 128 + ((gran ^ (row & 7)) << 4);
}

// stage one 8KB round of a [rows][128B] tile: linear LDS dest (gload_lds
// requirement), inverse-swizzled global source. granules 0..3 = hi k-octets,
// 4..7 = lo. (r4/r7-proven staging function)
__device__ __forceinline__ void stage(char* ldsbase, const f16* hi, const f16* lo,
                                      int gbase, int k0, int r, int tid) {
    const int o   = (r * 512 + tid) * 16;
    const int row = o >> 7;
    const int gp  = (o >> 4) & 7;
    const int g   = gp ^ (row & 7);
    const f16* src = (g < 4 ? hi : lo) + (size_t)(gbase + row) * KH + k0 + (g & 3) * 8;
    async16(ldsbase + o, src);
}

// ---------------- fused gates GEMM + logits + XG gather + LSTM cell ---------
// 256x256 tile, 8 waves (2Mx4N), per-wave 128x64 via 16x16x32, fp16 hi/lo
// 3-pass. Double-buffered K-tile=32. Counted waits: top vmcnt(4) (A4+Wo1
// ready), mid vmcnt(5) (B4 ready) -- never drains in the loop.
// NEW: W_out staged as third operand (8KB/tile); acc_l accumulates
// logits(t-1) = W_out . h_t alongside the gates. Post-loop: in-LDS softmax/
// argmax (local sAm -> no ambuf round-trip); bx==0 writes omsg/odig/ologp.
__global__ __launch_bounds__(512, 1) void gemm_fused(
    const f16* __restrict__ Hh, const f16* __restrict__ Hl,
    const f16* __restrict__ Whi, const f16* __restrict__ Wlo,
    const f16* __restrict__ Wohi, const f16* __restrict__ Wolo,
    const float* __restrict__ XG, const float* __restrict__ b_out,
    float* __restrict__ cbuf,
    f16* __restrict__ HhN, f16* __restrict__ HlN,
    float* __restrict__ omsg0, float* __restrict__ odig0,
    float* __restrict__ ologp, int t)
{
    __shared__ char smem[147456];   // A dbuf 64K | B dbuf 64K | Wo dbuf 16K
    __shared__ int sAm[256];

    const int tid  = threadIdx.x;
    const int lane = tid & 63;
    const int wv   = tid >> 6;          // 0..7
    const int wm   = wv >> 2;           // 0..1 (128-row half)
    const int wn   = wv & 3;            // 0..3 (64-col quarter)
    const int bx   = blockIdx.x;        // 0..15 (gate cols)
    const int by   = blockIdx.y;        // 0..15 (batch rows)
    const int bm   = by * 256;
    const int bnp  = bx * 256;
    const int rl   = lane & 15;
    const int kg   = lane >> 4;         // k-octet 0..3

    f32x4 acc[8][4];
    f32x4 acc_l[8];
#pragma unroll
    for (int i = 0; i < 8; ++i) {
#pragma unroll
        for (int g = 0; g < 4; ++g) acc[i][g] = f32x4{0.f, 0.f, 0.f, 0.f};
        acc_l[i] = f32x4{0.f, 0.f, 0.f, 0.f};
    }

    // prologue: stage tile 0 (A4 + Wo1, then B4; order matters for vmcnt)
#pragma unroll
    for (int r = 0; r < 4; ++r) stage(smem,          Hh,   Hl,   bm,  0, r, tid);
    stage(smem + 131072,                             Wohi, Wolo, 0,   0, 0, tid);
#pragma unroll
    for (int r = 0; r < 4; ++r) stage(smem + 65536,  Whi,  Wlo,  bnp, 0, r, tid);

    for (int kt = 0; kt < 32; ++kt) {
        const char* cb  = smem + (kt & 1) * 32768;
        const char* cbB = smem + 65536 + (kt & 1) * 32768;
        const char* cbW = smem + 131072 + (kt & 1) * 8192;
        char* nb  = smem + ((kt + 1) & 1) * 32768;
        char* nbB = smem + 65536 + ((kt + 1) & 1) * 32768;
        char* nbW = smem + 131072 + ((kt + 1) & 1) * 8192;
        const int kn = ((kt + 1) & 31) * 32;    // wrap at last tile (junk into dead buf)

        // top: A4+Wo1 of this tile must be ready; prev B-units may fly
        asm volatile("s_waitcnt vmcnt(4)" ::: "memory");
        asm volatile("s_barrier" ::: "memory");

        // stage next tile's A4 + Wo1 (5 loads/thread)
#pragma unroll
        for (int r = 0; r < 4; ++r) stage(nb, Hh, Hl, bm, kn, r, tid);
        stage(nbW, Wohi, Wolo, 0, kn, 0, tid);

        // mid: B4 of this tile must be ready; my new A-stages may fly
        asm volatile("s_waitcnt vmcnt(5)" ::: "memory");
        asm volatile("s_barrier" ::: "memory");

        f16x8 bh[4], bl[4];
#pragma unroll
        for (int f = 0; f < 4; ++f) {
            const int row = wn * 64 + f * 16 + rl;
            bh[f] = *(const f16x8*)(cbB + swz(row, kg));
            bl[f] = *(const f16x8*)(cbB + swz(row, kg + 4));
        }
        const f16x8 woh = *(const f16x8*)(cbW + swz(wn * 16 + rl, kg));
        const f16x8 wol = *(const f16x8*)(cbW + swz(wn * 16 + rl, kg + 4));
        // stage next tile's B4
#pragma unroll
        for (int r = 0; r < 4; ++r) stage(nbB, Whi, Wlo, bnp, kn, r, tid);

        __builtin_amdgcn_s_setprio(1);
#pragma unroll
        for (int f = 0; f < 8; ++f) {
            const int row = wm * 128 + f * 16 + rl;
            const f16x8 ah = *(const f16x8*)(cb + swz(row, kg));
            const f16x8 al = *(const f16x8*)(cb + swz(row, kg + 4));
#pragma unroll
            for (int g = 0; g < 4; ++g) {
                acc[f][g] = __builtin_amdgcn_mfma_f32_16x16x32_f16(ah, bh[g], acc[f][g], 0, 0, 0);
                acc[f][g] = __builtin_amdgcn_mfma_f32_16x16x32_f16(ah, bl[g], acc[f][g], 0, 0, 0);
                acc[f][g] = __builtin_amdgcn_mfma_f32_16x16x32_f16(al, bh[g], acc[f][g], 0, 0, 0);
            }
            acc_l[f] = __builtin_amdgcn_mfma_f32_16x16x32_f16(ah, woh, acc_l[f], 0, 0, 0);
            acc_l[f] = __builtin_amdgcn_mfma_f32_16x16x32_f16(ah, wol, acc_l[f], 0, 0, 0);
            acc_l[f] = __builtin_amdgcn_mfma_f32_16x16x32_f16(al, woh, acc_l[f], 0, 0, 0);
        }
        __builtin_amdgcn_s_setprio(0);
    }

    // drain junk prefetch before reusing LDS
    asm volatile("s_waitcnt vmcnt(0)" ::: "memory");
    __syncthreads();

    const int q = lane >> 4;

    // ---- logits(t-1) phase: in-LDS softmax/argmax, local sAm ----
    float* sL = (float*)smem;                   // [256][65] f32 (66.5 KB)
    if (t > 0) {
        const int ti = t - 1;
        const float bo = b_out[wn * 16 + rl];
#pragma unroll
        for (int f = 0; f < 8; ++f)
#pragma unroll
            for (int rg = 0; rg < 4; ++rg) {
                const int row = wm * 128 + f * 16 + q * 4 + rg;
                sL[row * 65 + wn * 16 + rl] = acc_l[f][rg] + bo;
            }
        __syncthreads();
        if (tid < 256) {
            const int row = tid;
            float m = -1e30f; int am = 0;
#pragma unroll 8
            for (int c = 0; c < 64; ++c) {
                const float v = sL[row * 65 + c];
                if (v > m) { m = v; am = c; }
            }
            float s = 0.f;
#pragma unroll 8
            for (int c = 0; c < 64; ++c)
                s += __builtin_amdgcn_exp2f(1.44269504088896f * (sL[row * 65 + c] - m));
            sAm[row] = am;
            if (bx == 0) {
                const float prev = (ti == 0) ? 0.f : ologp[bm + row];
                ologp[bm + row] = prev - logf(s);   // log p[argmax] = -log sum exp(l-m)
            }
        }
        __syncthreads();
        if (bx == 0) {
            float* omsg = omsg0 + (size_t)ti * BATCH * VOC;
            float* odig = odig0 + (size_t)ti * BATCH * VOC;
#pragma unroll
            for (int i = 0; i < 8; ++i) {
                const int idx = i * 512 + tid;
                const int row = idx >> 6;
                const int c   = idx & 63;
                odig[(size_t)(bm + row) * VOC + c] = sL[row * 65 + c];
                omsg[(size_t)(bm + row) * VOC + c] = (c == sAm[row]) ? 1.0f : 0.0f;
            }
        }
        __syncthreads();
    } else {
        if (tid < 256) sAm[tid] = 64;
        __syncthreads();
    }

    // ---- epilogue (r9-verified): XG slice -> LDS, fast cell, h via LDS ----
    float* sXG = (float*)smem;                  // [65][256] f32 (66.5 KB)
    f16*   hHi = (f16*)(smem + 66560);          // [256][64] (32 KB)
    f16*   hLo = (f16*)(smem + 99328);          // [256][64] (32 KB)
    const int jb = bx * 64;                     // j column base

#pragma unroll
    for (int i = 0; i < 9; ++i) {
        const int idx = i * 512 + tid;          // float4 units; need 65*64=4160
        if (idx < 65 * 64) {
            const int v  = idx >> 6;
            const int c4 = (idx & 63) * 4;
            *(float4*)&sXG[v * 256 + c4] =
                *(const float4*)&XG[(size_t)v * NG + bnp + c4];
        }
    }
    __syncthreads();

    const int lcol = wn * 16 + rl;
    const int jglob = jb + lcol;
#pragma unroll
    for (int i = 0; i < 8; ++i) {
#pragma unroll
        for (int rg = 0; rg < 4; ++rg) {
            const int lrow = wm * 128 + i * 16 + q * 4 + rg;
            const int v = sAm[lrow];
            const float4 xg = *(const float4*)&sXG[v * 256 + lcol * 4];
            const size_t ci = (size_t)(bm + lrow) * HD + jglob;
            const float cold = cbuf[ci];
            const float I = sigm_f(acc[i][0][rg] + xg.x);
            const float F = sigm_f(acc[i][1][rg] + xg.y);
            const float G = tanh_f(acc[i][2][rg] + xg.z);
            const float O = sigm_f(acc[i][3][rg] + xg.w);
            const float cc = F * cold + I * G;
            const float hh = O * tanh_f(cc);
            cbuf[ci] = cc;
            f16 hi_, lo_;
            splt(hh, hi_, lo_);
            hHi[lrow * 64 + lcol] = hi_;
            hLo[lrow * 64 + lcol] = lo_;
        }
    }
    __syncthreads();

    // coalesced h write-out
#pragma unroll
    for (int r = 0; r < 8; ++r) {
        const int idx = r * 512 + tid;
        const int row = idx >> 4;
        const int c4  = (idx & 15) * 4;
        *(f16x4*)&HhN[(size_t)(bm + row) * HD + jb + c4] = *(f16x4*)&hHi[row * 64 + c4];
        *(f16x4*)&HlN[(size_t)(bm + row) * HD + jb + c4] = *(f16x4*)&hLo[row * 64 + c4];
    }
}

// ---------------- final logits (t = MSGL-1 uses h_16) ------------------------
__global__ __launch_bounds__(256) void logits_step(
    const f16* __restrict__ Hh, const f16* __restrict__ Hl,
    const float* __restrict__ W_outT, const float* __restrict__ b_out,
    float* __restrict__ omsg, float* __restrict__ odig,
    float* __restrict__ ologp, int t)
{
    const int lane = threadIdx.x & 63;
    const int wv   = threadIdx.x >> 6;
    const int r0   = blockIdx.x * 8 + wv * 2;

    float a0 = 0.f, a1 = 0.f;
    const f16* hh0 = Hh + (size_t)r0 * HD;
    const f16* hl0 = Hl + (size_t)r0 * HD;
    const f16* hh1 = hh0 + HD;
    const f16* hl1 = hl0 + HD;
    for (int k = 0; k < HD; k += 4) {
        const float w0 = W_outT[(k + 0) * 64 + lane];
        const float w1 = W_outT[(k + 1) * 64 + lane];
        const float w2 = W_outT[(k + 2) * 64 + lane];
        const float w3 = W_outT[(k + 3) * 64 + lane];
        const f16x4 vh0 = *(const f16x4*)&hh0[k];
        const f16x4 vl0 = *(const f16x4*)&hl0[k];
        const f16x4 vh1 = *(const f16x4*)&hh1[k];
        const f16x4 vl1 = *(const f16x4*)&hl1[k];
        a0 += w0 * ((float)vh0[0] + (float)vl0[0]) + w1 * ((float)vh0[1] + (float)vl0[1])
            + w2 * ((float)vh0[2] + (float)vl0[2]) + w3 * ((float)vh0[3] + (float)vl0[3]);
        a1 += w0 * ((float)vh1[0] + (float)vl1[0]) + w1 * ((float)vh1[1] + (float)vl1[1])
            + w2 * ((float)vh1[2] + (float)vl1[2]) + w3 * ((float)vh1[3] + (float)vl1[3]);
    }
    const float bo = b_out[lane];
    const float accs[2] = {a0, a1};

#pragma unroll
    for (int r = 0; r < 2; ++r) {
        const int row = r0 + r;
        const float lg = accs[r] + bo;

        float m = lg; int am = lane;
#pragma unroll
        for (int d = 1; d < 64; d <<= 1) {
            const float om = __shfl_xor(m, d);
            const int   oa = __shfl_xor(am, d);
            if (om > m || (om == m && oa < am)) { m = om; am = oa; }
        }
        float s = expf(lg - m);
#pragma unroll
        for (int d = 1; d < 64; d <<= 1) s += __shfl_xor(s, d);

        odig[(size_t)row * VOC + lane] = lg;
        omsg[(size_t)row * VOC + lane] = (lane == am) ? 1.0f : 0.0f;
        if (lane == 0) {
            const float prev = (t == 0) ? 0.0f : ologp[row];
            ologp[row] = prev - logf(s);
        }
    }
}

// ---------------- XG table: XG[v][j*4+g] = relu(x_v)@W_ih^T + b_ih + b_hh ---
__global__ __launch_bounds__(256) void xg_kernel(
    const float* __restrict__ W_ih, const float* __restrict__ rembT,  // [1024][64]
    const float* __restrict__ rembX0, const float* __restrict__ bR,
    float* __restrict__ XG)                                           // [65][4096]
{
    __shared__ float sW[4][1024];
    const int lane = threadIdx.x & 63;
    const int wv   = threadIdx.x >> 6;
    const int np   = blockIdx.x * 4 + wv;
    const int orig = orig_n(np);
    const float* wr = W_ih + (size_t)orig * HD;
#pragma unroll
    for (int c = 0; c < 4; ++c)
        *(float4*)&sW[wv][c * 256 + lane * 4] = *(const float4*)&wr[c * 256 + lane * 4];
    __syncthreads();

    float acc = 0.f, acc0 = 0.f;
#pragma unroll 4
    for (int k = 0; k < HD; ++k) {
        const float w = sW[wv][k];
        acc  += w * rembT[k * 64 + lane];
        acc0 += w * rembX0[k];
    }
    const float b = bR[np];
    const int g = (np >> 4) & 3;
    const int pos = j_of(np) * 4 + g;
    XG[(size_t)lane * NG + pos] = acc + b;
    if (lane == 0) XG[(size_t)64 * NG + pos] = acc0 + b;
}

// ---------------- prep kernels ----------------------------------------------
__global__ __launch_bounds__(256) void prep_w(
    const float* __restrict__ W_hh, f16* __restrict__ Whi, f16* __restrict__ Wlo)
{
    const long long idx = ((long long)blockIdx.x * 256 + threadIdx.x) * 4; // NG*KH
    const int np = (int)(idx >> 10);
    const int k  = (int)(idx & 1023);
    const float4 v = *(const float4*)&W_hh[(size_t)orig_n(np) * HD + k];
    f16x4 vh, vl; f16 hi_, lo_;
    splt(v.x, hi_, lo_); vh[0] = hi_; vl[0] = lo_;
    splt(v.y, hi_, lo_); vh[1] = hi_; vl[1] = lo_;
    splt(v.z, hi_, lo_); vh[2] = hi_; vl[2] = lo_;
    splt(v.w, hi_, lo_); vh[3] = hi_; vl[3] = lo_;
    *(f16x4*)&Whi[idx] = vh;
    *(f16x4*)&Wlo[idx] = vl;
}

__global__ __launch_bounds__(256) void prep_h(
    const float* __restrict__ ench, f16* __restrict__ Hh, f16* __restrict__ Hl)
{
    const int idx = (blockIdx.x * 256 + threadIdx.x) * 4;   // BATCH*HD
    const float4 v = *(const float4*)&ench[idx];
    f16x4 vh, vl; f16 hi_, lo_;
    splt(v.x, hi_, lo_); vh[0] = hi_; vl[0] = lo_;
    splt(v.y, hi_, lo_); vh[1] = hi_; vl[1] = lo_;
    splt(v.z, hi_, lo_); vh[2] = hi_; vl[2] = lo_;
    splt(v.w, hi_, lo_); vh[3] = hi_; vl[3] = lo_;
    *(f16x4*)&Hh[idx] = vh;
    *(f16x4*)&Hl[idx] = vl;
}

__global__ __launch_bounds__(256) void prep_c(
    const float* __restrict__ encc, float* __restrict__ cbuf)
{
    const int idx = (blockIdx.x * 256 + threadIdx.x) * 4;
    *(float4*)&cbuf[idx] = *(const float4*)&encc[idx];
}

// mask, W_out transpose + hi/lo split, relu(emb) transpose, relu(x0), bias
__global__ __launch_bounds__(256) void prep_small(
    const float* __restrict__ W_out, const float* __restrict__ b_ih,
    const float* __restrict__ b_hh, const float* __restrict__ emb,
    const float* __restrict__ x0,
    float* __restrict__ W_outT, f16* __restrict__ Wohi, f16* __restrict__ Wolo,
    float* __restrict__ rembT,
    float* __restrict__ rembX0, float* __restrict__ bR, float* __restrict__ mask)
{
    const int i = blockIdx.x * 256 + threadIdx.x;   // 0..65535
    mask[i] = 1.0f;
    const int v = i >> 10, k = i & 1023;
    const float wo = W_out[i];
    W_outT[k * 64 + v] = wo;
    f16 hi2, lo2; splt(wo, hi2, lo2);
    Wohi[i] = hi2; Wolo[i] = lo2;                   // [64][1024] row-major
    rembT[k * 64 + v] = fmaxf(emb[i], 0.f);
    if (i < 1024) rembX0[i] = fmaxf(x0[i], 0.f);
    if (i < NG) {
        const int orig = orig_n(i);
        bR[i] = b_ih[orig] + b_hh[orig];
    }
}

// ---------------- launch ----------------------------------------------------
extern "C" void kernel_launch(void* const* d_in, const int* in_sizes, int n_in,
                              void* d_out, int out_size, void* d_ws, size_t ws_size,
                              hipStream_t stream)
{
    const float* ench  = (const float*)d_in[0];
    const float* encc  = (const float*)d_in[1];
    const float* W_ih  = (const float*)d_in[2];
    const float* W_hh  = (const float*)d_in[3];
    const float* b_ih  = (const float*)d_in[4];
    const float* b_hh  = (const float*)d_in[5];
    const float* W_out = (const float*)d_in[6];
    const float* b_out = (const float*)d_in[7];
    const float* x0    = (const float*)d_in[8];
    const float* emb   = (const float*)d_in[9];
    float* out = (float*)d_out;

    char* ws = (char*)d_ws;
    f16*   Hh[2]  = { (f16*)(ws + ((size_t) 0 << 20)), (f16*)(ws + ((size_t)16 << 20)) };
    f16*   Hl[2]  = { (f16*)(ws + ((size_t) 8 << 20)), (f16*)(ws + ((size_t)24 << 20)) };
    f16*   Whr    = (f16*)(ws + ((size_t)32 << 20));
    f16*   Wlr    = (f16*)(ws + ((size_t)40 << 20));
    float* cbuf   = (float*)(ws + ((size_t)48 << 20));
    float* W_outT = (float*)(ws + ((size_t)64 << 20));
    float* rembT  = (float*)(ws + ((size_t)65 << 20));
    float* rembX0 = (float*)(ws + ((size_t)66 << 20));
    float* bR     = (float*)(ws + ((size_t)66 << 20) + 8192);
    float* XG     = (float*)(ws + ((size_t)67 << 20));
    f16*   Wohi   = (f16*)(ws + ((size_t)70 << 20));
    f16*   Wolo   = (f16*)(ws + ((size_t)71 << 20));

    float* out_msg0 = out;                                        // [L,B,V]
    float* out_mask = out + (size_t)MSGL * BATCH * VOC;           // [L,1,B]
    float* out_dig0 = out_mask + (size_t)MSGL * BATCH;            // [L,B,V]
    float* out_logp = out_dig0 + (size_t)MSGL * BATCH * VOC;      // [B]

    prep_w<<<4096, 256, 0, stream>>>(W_hh, Whr, Wlr);
    prep_h<<<4096, 256, 0, stream>>>(ench, Hh[0], Hl[0]);
    prep_c<<<4096, 256, 0, stream>>>(encc, cbuf);
    prep_small<<<256, 256, 0, stream>>>(W_out, b_ih, b_hh, emb, x0,
                                        W_outT, Wohi, Wolo, rembT, rembX0, bR,
                                        out_mask);
    xg_kernel<<<1024, 256, 0, stream>>>(W_ih, rembT, rembX0, bR, XG);

    for (int t = 0; t < MSGL; ++t) {
        const int cur = t & 1, nxt = cur ^ 1;
        gemm_fused<<<dim3(16, 16), 512, 0, stream>>>(
            Hh[cur], Hl[cur], Whr, Wlr, Wohi, Wolo, XG, b_out,
            cbuf, Hh[nxt], Hl[nxt],
            out_msg0, out_dig0, out_logp, t);
    }
    // final step's logits use h_16 (written by gemm t=15 into Hh[0]/Hl[0])
    logits_step<<<512, 256, 0, stream>>>(
        Hh[0], Hl[0], W_outT, b_out,
        out_msg0 + (size_t)(MSGL - 1) * BATCH * VOC,
        out_dig0 + (size_t)(MSGL - 1) * BATCH * VOC,
        out_logp, MSGL - 1);
}

// Round 14
// 1941.512 us; speedup vs baseline: 2.9447x; 1.0022x over previous
//
#include <hip/hip_runtime.h>
#include <math.h>

#define HD    1024
#define BATCH 4096
#define VOC   64
#define MSGL  16
#define KH    1024   // GEMM K = hidden only (x-half folded into XG table)
#define NG    4096   // gates width = 4H

typedef _Float16 f16;
typedef _Float16 f16x8 __attribute__((ext_vector_type(8)));
typedef _Float16 f16x4 __attribute__((ext_vector_type(4)));
typedef float    f32x4 __attribute__((ext_vector_type(4)));

__device__ __forceinline__ void splt(float v, f16& hi, f16& lo) {
    f16 h = (f16)v;
    hi = h;
    lo = (f16)(v - (float)h);
}

// fast sigmoid/tanh via v_exp_f32 (2^x) + v_rcp_f32; error ~3e-7
__device__ __forceinline__ float sigm_f(float x) {
    return __builtin_amdgcn_rcpf(1.0f + __builtin_amdgcn_exp2f(-1.44269504088896f * x));
}
__device__ __forceinline__ float tanh_f(float x) {
    return 1.0f - 2.0f * __builtin_amdgcn_rcpf(1.0f + __builtin_amdgcn_exp2f(2.88539008177793f * x));
}

// permuted gate index (256-col tiles):
//   n' = bxx*256 + jh*64 + g*16 + cn   (bxx=n'>>8, jh 0..3, g 0..3, cn 0..15)
//   j  = bxx*64 + jh*16 + cn,  orig n = g*1024 + j
__device__ __forceinline__ int orig_n(int np) {
    const int bxx = np >> 8, rem = np & 255;
    const int jh = rem >> 6, g = (rem >> 4) & 3, cnn = rem & 15;
    return g * 1024 + bxx * 64 + jh * 16 + cnn;
}
__device__ __forceinline__ int j_of(int np) {
    const int bxx = np >> 8, rem = np & 255;
    const int jh = rem >> 6, cnn = rem & 15;
    return bxx * 64 + jh * 16 + cnn;
}

__device__ __forceinline__ void async16(void* lds, const void* g) {
    __builtin_amdgcn_global_load_lds(
        (const __attribute__((address_space(1))) void*)g,
        (__attribute__((address_space(3))) void*)lds, 16, 0, 0);
}

// swizzled byte offset in a [rows][128B-row] LDS tile; granule = 16B unit 0..7
// (r4/r7-proven layout)
__device__ __forceinline__ int swz(int row, int gran) {
    return row * 128 + ((gran ^ (row & 7)) << 4);
}

// stage one 8KB round of a [rows][128B] tile: linear LDS dest (gload_lds
// requirement), inverse-swizzled global source. granules 0..3 = hi k-octets,
// 4..7 = lo. (r4/r7-proven staging function)
__device__ __forceinline__ void stage(char* ldsbase, const f16* hi, const f16* lo,
                                      int gbase, int k0, int r, int tid) {
    const int o   = (r * 512 + tid) * 16;
    const int row = o >> 7;
    const int gp  = (o >> 4) & 7;
    const int g   = gp ^ (row & 7);
    const f16* src = (g < 4 ? hi : lo) + (size_t)(gbase + row) * KH + k0 + (g & 3) * 8;
    async16(ldsbase + o, src);
}

// ---------------- fused gates GEMM + logits + XG gather + LSTM cell ---------
// (r13-verified, byte-identical) 256x256 tile, 8 waves (2Mx4N), per-wave
// 128x64 via 16x16x32, fp16 hi/lo 3-pass. Double-buffered K-tile=32.
// Counted waits: top vmcnt(4) (A4+Wo1 ready), mid vmcnt(5) (B4 ready).
// W_out staged as third operand; acc_l = logits(t-1) = W_out . h_t.
// Post-loop in-LDS softmax/argmax (local sAm); bx==0 writes outputs.
__global__ __launch_bounds__(512, 1) void gemm_fused(
    const f16* __restrict__ Hh, const f16* __restrict__ Hl,
    const f16* __restrict__ Whi, const f16* __restrict__ Wlo,
    const f16* __restrict__ Wohi, const f16* __restrict__ Wolo,
    const float* __restrict__ XG, const float* __restrict__ b_out,
    float* __restrict__ cbuf,
    f16* __restrict__ HhN, f16* __restrict__ HlN,
    float* __restrict__ omsg0, float* __restrict__ odig0,
    float* __restrict__ ologp, int t)
{
    __shared__ char smem[147456];   // A dbuf 64K | B dbuf 64K | Wo dbuf 16K
    __shared__ int sAm[256];

    const int tid  = threadIdx.x;
    const int lane = tid & 63;
    const int wv   = tid >> 6;          // 0..7
    const int wm   = wv >> 2;           // 0..1 (128-row half)
    const int wn   = wv & 3;            // 0..3 (64-col quarter)
    const int bx   = blockIdx.x;        // 0..15 (gate cols)
    const int by   = blockIdx.y;        // 0..15 (batch rows)
    const int bm   = by * 256;
    const int bnp  = bx * 256;
    const int rl   = lane & 15;
    const int kg   = lane >> 4;         // k-octet 0..3

    f32x4 acc[8][4];
    f32x4 acc_l[8];
#pragma unroll
    for (int i = 0; i < 8; ++i) {
#pragma unroll
        for (int g = 0; g < 4; ++g) acc[i][g] = f32x4{0.f, 0.f, 0.f, 0.f};
        acc_l[i] = f32x4{0.f, 0.f, 0.f, 0.f};
    }

    // prologue: stage tile 0 (A4 + Wo1, then B4; order matters for vmcnt)
#pragma unroll
    for (int r = 0; r < 4; ++r) stage(smem,          Hh,   Hl,   bm,  0, r, tid);
    stage(smem + 131072,                             Wohi, Wolo, 0,   0, 0, tid);
#pragma unroll
    for (int r = 0; r < 4; ++r) stage(smem + 65536,  Whi,  Wlo,  bnp, 0, r, tid);

    for (int kt = 0; kt < 32; ++kt) {
        const char* cb  = smem + (kt & 1) * 32768;
        const char* cbB = smem + 65536 + (kt & 1) * 32768;
        const char* cbW = smem + 131072 + (kt & 1) * 8192;
        char* nb  = smem + ((kt + 1) & 1) * 32768;
        char* nbB = smem + 65536 + ((kt + 1) & 1) * 32768;
        char* nbW = smem + 131072 + ((kt + 1) & 1) * 8192;
        const int kn = ((kt + 1) & 31) * 32;    // wrap at last tile (junk into dead buf)

        // top: A4+Wo1 of this tile must be ready; prev B-units may fly
        asm volatile("s_waitcnt vmcnt(4)" ::: "memory");
        asm volatile("s_barrier" ::: "memory");

        // stage next tile's A4 + Wo1 (5 loads/thread)
#pragma unroll
        for (int r = 0; r < 4; ++r) stage(nb, Hh, Hl, bm, kn, r, tid);
        stage(nbW, Wohi, Wolo, 0, kn, 0, tid);

        // mid: B4 of this tile must be ready; my new A-stages may fly
        asm volatile("s_waitcnt vmcnt(5)" ::: "memory");
        asm volatile("s_barrier" ::: "memory");

        f16x8 bh[4], bl[4];
#pragma unroll
        for (int f = 0; f < 4; ++f) {
            const int row = wn * 64 + f * 16 + rl;
            bh[f] = *(const f16x8*)(cbB + swz(row, kg));
            bl[f] = *(const f16x8*)(cbB + swz(row, kg + 4));
        }
        const f16x8 woh = *(const f16x8*)(cbW + swz(wn * 16 + rl, kg));
        const f16x8 wol = *(const f16x8*)(cbW + swz(wn * 16 + rl, kg + 4));
        // stage next tile's B4
#pragma unroll
        for (int r = 0; r < 4; ++r) stage(nbB, Whi, Wlo, bnp, kn, r, tid);

        __builtin_amdgcn_s_setprio(1);
#pragma unroll
        for (int f = 0; f < 8; ++f) {
            const int row = wm * 128 + f * 16 + rl;
            const f16x8 ah = *(const f16x8*)(cb + swz(row, kg));
            const f16x8 al = *(const f16x8*)(cb + swz(row, kg + 4));
#pragma unroll
            for (int g = 0; g < 4; ++g) {
                acc[f][g] = __builtin_amdgcn_mfma_f32_16x16x32_f16(ah, bh[g], acc[f][g], 0, 0, 0);
                acc[f][g] = __builtin_amdgcn_mfma_f32_16x16x32_f16(ah, bl[g], acc[f][g], 0, 0, 0);
                acc[f][g] = __builtin_amdgcn_mfma_f32_16x16x32_f16(al, bh[g], acc[f][g], 0, 0, 0);
            }
            acc_l[f] = __builtin_amdgcn_mfma_f32_16x16x32_f16(ah, woh, acc_l[f], 0, 0, 0);
            acc_l[f] = __builtin_amdgcn_mfma_f32_16x16x32_f16(ah, wol, acc_l[f], 0, 0, 0);
            acc_l[f] = __builtin_amdgcn_mfma_f32_16x16x32_f16(al, woh, acc_l[f], 0, 0, 0);
        }
        __builtin_amdgcn_s_setprio(0);
    }

    // drain junk prefetch before reusing LDS
    asm volatile("s_waitcnt vmcnt(0)" ::: "memory");
    __syncthreads();

    const int q = lane >> 4;

    // ---- logits(t-1) phase: in-LDS softmax/argmax, local sAm ----
    float* sL = (float*)smem;                   // [256][65] f32 (66.5 KB)
    if (t > 0) {
        const int ti = t - 1;
        const float bo = b_out[wn * 16 + rl];
#pragma unroll
        for (int f = 0; f < 8; ++f)
#pragma unroll
            for (int rg = 0; rg < 4; ++rg) {
                const int row = wm * 128 + f * 16 + q * 4 + rg;
                sL[row * 65 + wn * 16 + rl] = acc_l[f][rg] + bo;
            }
        __syncthreads();
        if (tid < 256) {
            const int row = tid;
            float m = -1e30f; int am = 0;
#pragma unroll 8
            for (int c = 0; c < 64; ++c) {
                const float v = sL[row * 65 + c];
                if (v > m) { m = v; am = c; }
            }
            float s = 0.f;
#pragma unroll 8
            for (int c = 0; c < 64; ++c)
                s += __builtin_amdgcn_exp2f(1.44269504088896f * (sL[row * 65 + c] - m));
            sAm[row] = am;
            if (bx == 0) {
                const float prev = (ti == 0) ? 0.f : ologp[bm + row];
                ologp[bm + row] = prev - logf(s);   // log p[argmax] = -log sum exp(l-m)
            }
        }
        __syncthreads();
        if (bx == 0) {
            float* omsg = omsg0 + (size_t)ti * BATCH * VOC;
            float* odig = odig0 + (size_t)ti * BATCH * VOC;
#pragma unroll
            for (int i = 0; i < 8; ++i) {
                const int idx = i * 512 + tid;
                const int row = idx >> 6;
                const int c   = idx & 63;
                odig[(size_t)(bm + row) * VOC + c] = sL[row * 65 + c];
                omsg[(size_t)(bm + row) * VOC + c] = (c == sAm[row]) ? 1.0f : 0.0f;
            }
        }
        __syncthreads();
    } else {
        if (tid < 256) sAm[tid] = 64;
        __syncthreads();
    }

    // ---- epilogue (r9-verified): XG slice -> LDS, fast cell, h via LDS ----
    float* sXG = (float*)smem;                  // [65][256] f32 (66.5 KB)
    f16*   hHi = (f16*)(smem + 66560);          // [256][64] (32 KB)
    f16*   hLo = (f16*)(smem + 99328);          // [256][64] (32 KB)
    const int jb = bx * 64;                     // j column base

#pragma unroll
    for (int i = 0; i < 9; ++i) {
        const int idx = i * 512 + tid;          // float4 units; need 65*64=4160
        if (idx < 65 * 64) {
            const int v  = idx >> 6;
            const int c4 = (idx & 63) * 4;
            *(float4*)&sXG[v * 256 + c4] =
                *(const float4*)&XG[(size_t)v * NG + bnp + c4];
        }
    }
    __syncthreads();

    const int lcol = wn * 16 + rl;
    const int jglob = jb + lcol;
#pragma unroll
    for (int i = 0; i < 8; ++i) {
#pragma unroll
        for (int rg = 0; rg < 4; ++rg) {
            const int lrow = wm * 128 + i * 16 + q * 4 + rg;
            const int v = sAm[lrow];
            const float4 xg = *(const float4*)&sXG[v * 256 + lcol * 4];
            const size_t ci = (size_t)(bm + lrow) * HD + jglob;
            const float cold = cbuf[ci];
            const float I = sigm_f(acc[i][0][rg] + xg.x);
            const float F = sigm_f(acc[i][1][rg] + xg.y);
            const float G = tanh_f(acc[i][2][rg] + xg.z);
            const float O = sigm_f(acc[i][3][rg] + xg.w);
            const float cc = F * cold + I * G;
            const float hh = O * tanh_f(cc);
            cbuf[ci] = cc;
            f16 hi_, lo_;
            splt(hh, hi_, lo_);
            hHi[lrow * 64 + lcol] = hi_;
            hLo[lrow * 64 + lcol] = lo_;
        }
    }
    __syncthreads();

    // coalesced h write-out
#pragma unroll
    for (int r = 0; r < 8; ++r) {
        const int idx = r * 512 + tid;
        const int row = idx >> 4;
        const int c4  = (idx & 15) * 4;
        *(f16x4*)&HhN[(size_t)(bm + row) * HD + jb + c4] = *(f16x4*)&hHi[row * 64 + c4];
        *(f16x4*)&HlN[(size_t)(bm + row) * HD + jb + c4] = *(f16x4*)&hLo[row * 64 + c4];
    }
}

// ---------------- final logits (t = MSGL-1 uses h_16) ------------------------
__global__ __launch_bounds__(256) void logits_step(
    const f16* __restrict__ Hh, const f16* __restrict__ Hl,
    const float* __restrict__ W_outT, const float* __restrict__ b_out,
    float* __restrict__ omsg, float* __restrict__ odig,
    float* __restrict__ ologp, int t)
{
    const int lane = threadIdx.x & 63;
    const int wv   = threadIdx.x >> 6;
    const int r0   = blockIdx.x * 8 + wv * 2;

    float a0 = 0.f, a1 = 0.f;
    const f16* hh0 = Hh + (size_t)r0 * HD;
    const f16* hl0 = Hl + (size_t)r0 * HD;
    const f16* hh1 = hh0 + HD;
    const f16* hl1 = hl0 + HD;
    for (int k = 0; k < HD; k += 4) {
        const float w0 = W_outT[(k + 0) * 64 + lane];
        const float w1 = W_outT[(k + 1) * 64 + lane];
        const float w2 = W_outT[(k + 2) * 64 + lane];
        const float w3 = W_outT[(k + 3) * 64 + lane];
        const f16x4 vh0 = *(const f16x4*)&hh0[k];
        const f16x4 vl0 = *(const f16x4*)&hl0[k];
        const f16x4 vh1 = *(const f16x4*)&hh1[k];
        const f16x4 vl1 = *(const f16x4*)&hl1[k];
        a0 += w0 * ((float)vh0[0] + (float)vl0[0]) + w1 * ((float)vh0[1] + (float)vl0[1])
            + w2 * ((float)vh0[2] + (float)vl0[2]) + w3 * ((float)vh0[3] + (float)vl0[3]);
        a1 += w0 * ((float)vh1[0] + (float)vl1[0]) + w1 * ((float)vh1[1] + (float)vl1[1])
            + w2 * ((float)vh1[2] + (float)vl1[2]) + w3 * ((float)vh1[3] + (float)vl1[3]);
    }
    const float bo = b_out[lane];
    const float accs[2] = {a0, a1};

#pragma unroll
    for (int r = 0; r < 2; ++r) {
        const int row = r0 + r;
        const float lg = accs[r] + bo;

        float m = lg; int am = lane;
#pragma unroll
        for (int d = 1; d < 64; d <<= 1) {
            const float om = __shfl_xor(m, d);
            const int   oa = __shfl_xor(am, d);
            if (om > m || (om == m && oa < am)) { m = om; am = oa; }
        }
        float s = expf(lg - m);
#pragma unroll
        for (int d = 1; d < 64; d <<= 1) s += __shfl_xor(s, d);

        odig[(size_t)row * VOC + lane] = lg;
        omsg[(size_t)row * VOC + lane] = (lane == am) ? 1.0f : 0.0f;
        if (lane == 0) {
            const float prev = (t == 0) ? 0.0f : ologp[row];
            ologp[row] = prev - logf(s);
        }
    }
}

// ---------------- XG table: XG[v][j*4+g] = relu(x_v)@W_ih^T + b_ih + b_hh ---
__global__ __launch_bounds__(256) void xg_kernel(
    const float* __restrict__ W_ih, const float* __restrict__ rembT,  // [1024][64]
    const float* __restrict__ rembX0, const float* __restrict__ bR,
    float* __restrict__ XG)                                           // [65][4096]
{
    __shared__ float sW[4][1024];
    const int lane = threadIdx.x & 63;
    const int wv   = threadIdx.x >> 6;
    const int np   = blockIdx.x * 4 + wv;
    const int orig = orig_n(np);
    const float* wr = W_ih + (size_t)orig * HD;
#pragma unroll
    for (int c = 0; c < 4; ++c)
        *(float4*)&sW[wv][c * 256 + lane * 4] = *(const float4*)&wr[c * 256 + lane * 4];
    __syncthreads();

    float acc = 0.f, acc0 = 0.f;
#pragma unroll 4
    for (int k = 0; k < HD; ++k) {
        const float w = sW[wv][k];
        acc  += w * rembT[k * 64 + lane];
        acc0 += w * rembX0[k];
    }
    const float b = bR[np];
    const int g = (np >> 4) & 3;
    const int pos = j_of(np) * 4 + g;
    XG[(size_t)lane * NG + pos] = acc + b;
    if (lane == 0) XG[(size_t)64 * NG + pos] = acc0 + b;
}

// ---------------- merged prep: W split + h split + c copy + small tables ----
// 4096 blocks x 256 threads = 1M threads; each handles one float4 unit of
// each former prep kernel's index space (bodies unchanged from r13).
__global__ __launch_bounds__(256) void prep_all(
    const float* __restrict__ W_hh, const float* __restrict__ ench,
    const float* __restrict__ encc, const float* __restrict__ W_out,
    const float* __restrict__ b_ih, const float* __restrict__ b_hh,
    const float* __restrict__ emb, const float* __restrict__ x0,
    f16* __restrict__ Whi, f16* __restrict__ Wlo,
    f16* __restrict__ Hh, f16* __restrict__ Hl,
    float* __restrict__ cbuf,
    float* __restrict__ W_outT, f16* __restrict__ Wohi, f16* __restrict__ Wolo,
    float* __restrict__ rembT, float* __restrict__ rembX0,
    float* __restrict__ bR, float* __restrict__ mask)
{
    const int u = blockIdx.x * 256 + threadIdx.x;   // 0 .. 1M-1
    const long long idx = (long long)u * 4;

    // --- prep_w: W_hh permuted + hi/lo split (NG*KH elements) ---
    {
        const int np = (int)(idx >> 10);
        const int k  = (int)(idx & 1023);
        const float4 v = *(const float4*)&W_hh[(size_t)orig_n(np) * HD + k];
        f16x4 vh, vl; f16 hi_, lo_;
        splt(v.x, hi_, lo_); vh[0] = hi_; vl[0] = lo_;
        splt(v.y, hi_, lo_); vh[1] = hi_; vl[1] = lo_;
        splt(v.z, hi_, lo_); vh[2] = hi_; vl[2] = lo_;
        splt(v.w, hi_, lo_); vh[3] = hi_; vl[3] = lo_;
        *(f16x4*)&Whi[idx] = vh;
        *(f16x4*)&Wlo[idx] = vl;
    }
    // --- prep_h: encoder_hidden hi/lo split (BATCH*HD elements) ---
    {
        const float4 v = *(const float4*)&ench[idx];
        f16x4 vh, vl; f16 hi_, lo_;
        splt(v.x, hi_, lo_); vh[0] = hi_; vl[0] = lo_;
        splt(v.y, hi_, lo_); vh[1] = hi_; vl[1] = lo_;
        splt(v.z, hi_, lo_); vh[2] = hi_; vl[2] = lo_;
        splt(v.w, hi_, lo_); vh[3] = hi_; vl[3] = lo_;
        *(f16x4*)&Hh[idx] = vh;
        *(f16x4*)&Hl[idx] = vl;
    }
    // --- prep_c: encoder_cell copy ---
    *(float4*)&cbuf[idx] = *(const float4*)&encc[idx];

    // --- prep_small: mask, W_out transpose + hi/lo, relu(emb)T, relu(x0), bias
    if (u < 65536) {
        const int i = u;
        mask[i] = 1.0f;
        const int v = i >> 10, k = i & 1023;
        const float wo = W_out[i];
        W_outT[k * 64 + v] = wo;
        f16 hi2, lo2; splt(wo, hi2, lo2);
        Wohi[i] = hi2; Wolo[i] = lo2;               // [64][1024] row-major
        rembT[k * 64 + v] = fmaxf(emb[i], 0.f);
        if (i < 1024) rembX0[i] = fmaxf(x0[i], 0.f);
        if (i < NG) {
            const int orig = orig_n(i);
            bR[i] = b_ih[orig] + b_hh[orig];
        }
    }
}

// ---------------- launch ----------------------------------------------------
extern "C" void kernel_launch(void* const* d_in, const int* in_sizes, int n_in,
                              void* d_out, int out_size, void* d_ws, size_t ws_size,
                              hipStream_t stream)
{
    const float* ench  = (const float*)d_in[0];
    const float* encc  = (const float*)d_in[1];
    const float* W_ih  = (const float*)d_in[2];
    const float* W_hh  = (const float*)d_in[3];
    const float* b_ih  = (const float*)d_in[4];
    const float* b_hh  = (const float*)d_in[5];
    const float* W_out = (const float*)d_in[6];
    const float* b_out = (const float*)d_in[7];
    const float* x0    = (const float*)d_in[8];
    const float* emb   = (const float*)d_in[9];
    float* out = (float*)d_out;

    char* ws = (char*)d_ws;
    f16*   Hh[2]  = { (f16*)(ws + ((size_t) 0 << 20)), (f16*)(ws + ((size_t)16 << 20)) };
    f16*   Hl[2]  = { (f16*)(ws + ((size_t) 8 << 20)), (f16*)(ws + ((size_t)24 << 20)) };
    f16*   Whr    = (f16*)(ws + ((size_t)32 << 20));
    f16*   Wlr    = (f16*)(ws + ((size_t)40 << 20));
    float* cbuf   = (float*)(ws + ((size_t)48 << 20));
    float* W_outT = (float*)(ws + ((size_t)64 << 20));
    float* rembT  = (float*)(ws + ((size_t)65 << 20));
    float* rembX0 = (float*)(ws + ((size_t)66 << 20));
    float* bR     = (float*)(ws + ((size_t)66 << 20) + 8192);
    float* XG     = (float*)(ws + ((size_t)67 << 20));
    f16*   Wohi   = (f16*)(ws + ((size_t)70 << 20));
    f16*   Wolo   = (f16*)(ws + ((size_t)71 << 20));

    float* out_msg0 = out;                                        // [L,B,V]
    float* out_mask = out + (size_t)MSGL * BATCH * VOC;           // [L,1,B]
    float* out_dig0 = out_mask + (size_t)MSGL * BATCH;            // [L,B,V]
    float* out_logp = out_dig0 + (size_t)MSGL * BATCH * VOC;      // [B]

    prep_all<<<4096, 256, 0, stream>>>(
        W_hh, ench, encc, W_out, b_ih, b_hh, emb, x0,
        Whr, Wlr, Hh[0], Hl[0], cbuf,
        W_outT, Wohi, Wolo, rembT, rembX0, bR, out_mask);
    xg_kernel<<<1024, 256, 0, stream>>>(W_ih, rembT, rembX0, bR, XG);

    for (int t = 0; t < MSGL; ++t) {
        const int cur = t & 1, nxt = cur ^ 1;
        gemm_fused<<<dim3(16, 16), 512, 0, stream>>>(
            Hh[cur], Hl[cur], Whr, Wlr, Wohi, Wolo, XG, b_out,
            cbuf, Hh[nxt], Hl[nxt],
            out_msg0, out_dig0, out_logp, t);
    }
    // final step's logits use h_16 (written by gemm t=15 into Hh[0]/Hl[0])
    logits_step<<<512, 256, 0, stream>>>(
        Hh[0], Hl[0], W_outT, b_out,
        out_msg0 + (size_t)(MSGL - 1) * BATCH * VOC,
        out_dig0 + (size_t)(MSGL - 1) * BATCH * VOC,
        out_logp, MSGL - 1);
}

// Round 15
// 1915.371 us; speedup vs baseline: 2.9849x; 1.0136x over previous
//
#include <hip/hip_runtime.h>
#include <math.h>

#define HD    1024
#define BATCH 4096
#define VOC   64
#define MSGL  16
#define KH    1024   // GEMM K = hidden only (x-half folded into XG table)
#define NG    4096   // gates width = 4H

typedef _Float16 f16;
typedef _Float16 f16x8 __attribute__((ext_vector_type(8)));
typedef _Float16 f16x4 __attribute__((ext_vector_type(4)));
typedef float    f32x4 __attribute__((ext_vector_type(4)));

__device__ __forceinline__ void splt(float v, f16& hi, f16& lo) {
    f16 h = (f16)v;
    hi = h;
    lo = (f16)(v - (float)h);
}

// fast sigmoid/tanh via v_exp_f32 (2^x) + v_rcp_f32; error ~3e-7
__device__ __forceinline__ float sigm_f(float x) {
    return __builtin_amdgcn_rcpf(1.0f + __builtin_amdgcn_exp2f(-1.44269504088896f * x));
}
__device__ __forceinline__ float tanh_f(float x) {
    return 1.0f - 2.0f * __builtin_amdgcn_rcpf(1.0f + __builtin_amdgcn_exp2f(2.88539008177793f * x));
}

// permuted gate index (256-col tiles):
//   n' = bxx*256 + jh*64 + g*16 + cn   (bxx=n'>>8, jh 0..3, g 0..3, cn 0..15)
//   j  = bxx*64 + jh*16 + cn,  orig n = g*1024 + j
__device__ __forceinline__ int orig_n(int np) {
    const int bxx = np >> 8, rem = np & 255;
    const int jh = rem >> 6, g = (rem >> 4) & 3, cnn = rem & 15;
    return g * 1024 + bxx * 64 + jh * 16 + cnn;
}
__device__ __forceinline__ int j_of(int np) {
    const int bxx = np >> 8, rem = np & 255;
    const int jh = rem >> 6, cnn = rem & 15;
    return bxx * 64 + jh * 16 + cnn;
}

__device__ __forceinline__ void async16(void* lds, const void* g) {
    __builtin_amdgcn_global_load_lds(
        (const __attribute__((address_space(1))) void*)g,
        (__attribute__((address_space(3))) void*)lds, 16, 0, 0);
}

// swizzled byte offset in a [rows][128B-row] LDS tile; granule = 16B unit 0..7
// (r4/r7-proven layout)
__device__ __forceinline__ int swz(int row, int gran) {
    return row * 128 + ((gran ^ (row & 7)) << 4);
}

// stage one 8KB round (64 rows x 128B) of a [rows][128B] tile: linear LDS
// dest (gload_lds requirement), inverse-swizzled global source. granules
// 0..3 = hi k-octets, 4..7 = lo. (r4/r7-proven staging function)
__device__ __forceinline__ void stage(char* ldsbase, const f16* hi, const f16* lo,
                                      int gbase, int k0, int r, int tid) {
    const int o   = (r * 512 + tid) * 16;
    const int row = o >> 7;
    const int gp  = (o >> 4) & 7;
    const int g   = gp ^ (row & 7);
    const f16* src = (g < 4 ? hi : lo) + (size_t)(gbase + row) * KH + k0 + (g & 3) * 8;
    async16(ldsbase + o, src);
}

// ---------------- fused gates GEMM + logits + XG gather + LSTM cell ---------
// 256x256 tile, 8 waves (2Mx4N), per-wave 128x64 via 16x16x32, fp16 hi/lo
// 3-pass. Double-buffered K-tile=32. NEW (m201-faithful phase split):
// 4 quadrant-phases per K-tile -- phase q computes M-frags {2q,2q+1} x 4N x
// 3 passes + logits (30 MFMA); per phase {ds_read, stage slice, barrier,
// setprio-MFMA, [counted vmcnt], barrier}. B/Wo frags read once at phase 0,
// held in registers. Stage stream (for tile kt+1): B r0,r1+Wo @q0;
// B r2,r3 @q1; A r0,r2 @q2; A r1,r3 @q3. Waits: vmcnt(5) end-of-q1
// (A-second landed), vmcnt(2) end-of-q3 (next tile's B/Wo/A-first landed).
// Never drains below 2 in the loop; each load has >=2 phases of cover.
__global__ __launch_bounds__(512, 1) void gemm_fused(
    const f16* __restrict__ Hh, const f16* __restrict__ Hl,
    const f16* __restrict__ Whi, const f16* __restrict__ Wlo,
    const f16* __restrict__ Wohi, const f16* __restrict__ Wolo,
    const float* __restrict__ XG, const float* __restrict__ b_out,
    float* __restrict__ cbuf,
    f16* __restrict__ HhN, f16* __restrict__ HlN,
    float* __restrict__ omsg0, float* __restrict__ odig0,
    float* __restrict__ ologp, int t)
{
    __shared__ char smem[147456];   // A dbuf 64K | B dbuf 64K | Wo dbuf 16K
    __shared__ int sAm[256];

    const int tid  = threadIdx.x;
    const int lane = tid & 63;
    const int wv   = tid >> 6;          // 0..7
    const int wm   = wv >> 2;           // 0..1 (128-row half)
    const int wn   = wv & 3;            // 0..3 (64-col quarter)
    const int bx   = blockIdx.x;        // 0..15 (gate cols)
    const int by   = blockIdx.y;        // 0..15 (batch rows)
    const int bm   = by * 256;
    const int bnp  = bx * 256;
    const int rl   = lane & 15;
    const int kg   = lane >> 4;         // k-octet 0..3

    f32x4 acc[8][4];
    f32x4 acc_l[8];
#pragma unroll
    for (int i = 0; i < 8; ++i) {
#pragma unroll
        for (int g = 0; g < 4; ++g) acc[i][g] = f32x4{0.f, 0.f, 0.f, 0.f};
        acc_l[i] = f32x4{0.f, 0.f, 0.f, 0.f};
    }

    // prologue: stage tile 0 in steady-state stream order:
    // B r0, B r1, Wo, B r2, B r3, A r0, A r2, A r1, A r3  (9 loads)
    stage(smem + 65536,  Whi,  Wlo,  bnp, 0, 0, tid);
    stage(smem + 65536,  Whi,  Wlo,  bnp, 0, 1, tid);
    stage(smem + 131072, Wohi, Wolo, 0,   0, 0, tid);
    stage(smem + 65536,  Whi,  Wlo,  bnp, 0, 2, tid);
    stage(smem + 65536,  Whi,  Wlo,  bnp, 0, 3, tid);
    stage(smem,          Hh,   Hl,   bm,  0, 0, tid);
    stage(smem,          Hh,   Hl,   bm,  0, 2, tid);
    stage(smem,          Hh,   Hl,   bm,  0, 1, tid);
    stage(smem,          Hh,   Hl,   bm,  0, 3, tid);
    asm volatile("s_waitcnt vmcnt(2)" ::: "memory");   // A r1,r3 may still fly
    asm volatile("s_barrier" ::: "memory");

    for (int kt = 0; kt < 32; ++kt) {
        const char* cbA = smem + (kt & 1) * 32768;
        const char* cbB = smem + 65536 + (kt & 1) * 32768;
        const char* cbW = smem + 131072 + (kt & 1) * 8192;
        char* nbA = smem + ((kt + 1) & 1) * 32768;
        char* nbB = smem + 65536 + ((kt + 1) & 1) * 32768;
        char* nbW = smem + 131072 + ((kt + 1) & 1) * 8192;
        const int kn = ((kt + 1) & 31) * 32;    // wrap at last tile (junk into dead buf)

        f16x8 bh[4], bl[4], woh, wol;           // held across the 4 phases

#pragma unroll
        for (int q = 0; q < 4; ++q) {
            // ---- phase ds_reads (tile kt) ----
            f16x8 ah[2], al[2];
#pragma unroll
            for (int i = 0; i < 2; ++i) {
                const int row = wm * 128 + (2 * q + i) * 16 + rl;
                ah[i] = *(const f16x8*)(cbA + swz(row, kg));
                al[i] = *(const f16x8*)(cbA + swz(row, kg + 4));
            }
            if (q == 0) {
#pragma unroll
                for (int g = 0; g < 4; ++g) {
                    const int row = wn * 64 + g * 16 + rl;
                    bh[g] = *(const f16x8*)(cbB + swz(row, kg));
                    bl[g] = *(const f16x8*)(cbB + swz(row, kg + 4));
                }
                woh = *(const f16x8*)(cbW + swz(wn * 16 + rl, kg));
                wol = *(const f16x8*)(cbW + swz(wn * 16 + rl, kg + 4));
            }

            // ---- phase stage slice (tile kt+1) ----
            if (q == 0) {
                stage(nbB, Whi, Wlo, bnp, kn, 0, tid);
                stage(nbB, Whi, Wlo, bnp, kn, 1, tid);
                stage(nbW, Wohi, Wolo, 0, kn, 0, tid);
            } else if (q == 1) {
                stage(nbB, Whi, Wlo, bnp, kn, 2, tid);
                stage(nbB, Whi, Wlo, bnp, kn, 3, tid);
            } else if (q == 2) {
                stage(nbA, Hh, Hl, bm, kn, 0, tid);
                stage(nbA, Hh, Hl, bm, kn, 2, tid);
            } else {
                stage(nbA, Hh, Hl, bm, kn, 1, tid);
                stage(nbA, Hh, Hl, bm, kn, 3, tid);
            }

            asm volatile("s_barrier" ::: "memory");

            __builtin_amdgcn_s_setprio(1);
#pragma unroll
            for (int i = 0; i < 2; ++i) {
                const int f = 2 * q + i;
#pragma unroll
                for (int g = 0; g < 4; ++g) {
                    acc[f][g] = __builtin_amdgcn_mfma_f32_16x16x32_f16(ah[i], bh[g], acc[f][g], 0, 0, 0);
                    acc[f][g] = __builtin_amdgcn_mfma_f32_16x16x32_f16(ah[i], bl[g], acc[f][g], 0, 0, 0);
                    acc[f][g] = __builtin_amdgcn_mfma_f32_16x16x32_f16(al[i], bh[g], acc[f][g], 0, 0, 0);
                }
                acc_l[f] = __builtin_amdgcn_mfma_f32_16x16x32_f16(ah[i], woh, acc_l[f], 0, 0, 0);
                acc_l[f] = __builtin_amdgcn_mfma_f32_16x16x32_f16(ah[i], wol, acc_l[f], 0, 0, 0);
                acc_l[f] = __builtin_amdgcn_mfma_f32_16x16x32_f16(al[i], woh, acc_l[f], 0, 0, 0);
            }
            __builtin_amdgcn_s_setprio(0);

            // counted waits fold into phase-trailing barriers (m201 rhythm)
            if (q == 1) asm volatile("s_waitcnt vmcnt(5)" ::: "memory");
            if (q == 3) asm volatile("s_waitcnt vmcnt(2)" ::: "memory");
            asm volatile("s_barrier" ::: "memory");
        }
    }

    // drain junk prefetch before reusing LDS
    asm volatile("s_waitcnt vmcnt(0)" ::: "memory");
    __syncthreads();

    const int q = lane >> 4;

    // ---- logits(t-1) phase: in-LDS softmax/argmax, local sAm ----
    float* sL = (float*)smem;                   // [256][65] f32 (66.5 KB)
    if (t > 0) {
        const int ti = t - 1;
        const float bo = b_out[wn * 16 + rl];
#pragma unroll
        for (int f = 0; f < 8; ++f)
#pragma unroll
            for (int rg = 0; rg < 4; ++rg) {
                const int row = wm * 128 + f * 16 + q * 4 + rg;
                sL[row * 65 + wn * 16 + rl] = acc_l[f][rg] + bo;
            }
        __syncthreads();
        if (tid < 256) {
            const int row = tid;
            float m = -1e30f; int am = 0;
#pragma unroll 8
            for (int c = 0; c < 64; ++c) {
                const float v = sL[row * 65 + c];
                if (v > m) { m = v; am = c; }
            }
            float s = 0.f;
#pragma unroll 8
            for (int c = 0; c < 64; ++c)
                s += __builtin_amdgcn_exp2f(1.44269504088896f * (sL[row * 65 + c] - m));
            sAm[row] = am;
            if (bx == 0) {
                const float prev = (ti == 0) ? 0.f : ologp[bm + row];
                ologp[bm + row] = prev - logf(s);   // log p[argmax] = -log sum exp(l-m)
            }
        }
        __syncthreads();
        if (bx == 0) {
            float* omsg = omsg0 + (size_t)ti * BATCH * VOC;
            float* odig = odig0 + (size_t)ti * BATCH * VOC;
#pragma unroll
            for (int i = 0; i < 8; ++i) {
                const int idx = i * 512 + tid;
                const int row = idx >> 6;
                const int c   = idx & 63;
                odig[(size_t)(bm + row) * VOC + c] = sL[row * 65 + c];
                omsg[(size_t)(bm + row) * VOC + c] = (c == sAm[row]) ? 1.0f : 0.0f;
            }
        }
        __syncthreads();
    } else {
        if (tid < 256) sAm[tid] = 64;
        __syncthreads();
    }

    // ---- epilogue (r9-verified): XG slice -> LDS, fast cell, h via LDS ----
    float* sXG = (float*)smem;                  // [65][256] f32 (66.5 KB)
    f16*   hHi = (f16*)(smem + 66560);          // [256][64] (32 KB)
    f16*   hLo = (f16*)(smem + 99328);          // [256][64] (32 KB)
    const int jb = bx * 64;                     // j column base

#pragma unroll
    for (int i = 0; i < 9; ++i) {
        const int idx = i * 512 + tid;          // float4 units; need 65*64=4160
        if (idx < 65 * 64) {
            const int v  = idx >> 6;
            const int c4 = (idx & 63) * 4;
            *(float4*)&sXG[v * 256 + c4] =
                *(const float4*)&XG[(size_t)v * NG + bnp + c4];
        }
    }
    __syncthreads();

    const int lcol = wn * 16 + rl;
    const int jglob = jb + lcol;
#pragma unroll
    for (int i = 0; i < 8; ++i) {
#pragma unroll
        for (int rg = 0; rg < 4; ++rg) {
            const int lrow = wm * 128 + i * 16 + q * 4 + rg;
            const int v = sAm[lrow];
            const float4 xg = *(const float4*)&sXG[v * 256 + lcol * 4];
            const size_t ci = (size_t)(bm + lrow) * HD + jglob;
            const float cold = cbuf[ci];
            const float I = sigm_f(acc[i][0][rg] + xg.x);
            const float F = sigm_f(acc[i][1][rg] + xg.y);
            const float G = tanh_f(acc[i][2][rg] + xg.z);
            const float O = sigm_f(acc[i][3][rg] + xg.w);
            const float cc = F * cold + I * G;
            const float hh = O * tanh_f(cc);
            cbuf[ci] = cc;
            f16 hi_, lo_;
            splt(hh, hi_, lo_);
            hHi[lrow * 64 + lcol] = hi_;
            hLo[lrow * 64 + lcol] = lo_;
        }
    }
    __syncthreads();

    // coalesced h write-out
#pragma unroll
    for (int r = 0; r < 8; ++r) {
        const int idx = r * 512 + tid;
        const int row = idx >> 4;
        const int c4  = (idx & 15) * 4;
        *(f16x4*)&HhN[(size_t)(bm + row) * HD + jb + c4] = *(f16x4*)&hHi[row * 64 + c4];
        *(f16x4*)&HlN[(size_t)(bm + row) * HD + jb + c4] = *(f16x4*)&hLo[row * 64 + c4];
    }
}

// ---------------- final logits (t = MSGL-1 uses h_16) ------------------------
__global__ __launch_bounds__(256) void logits_step(
    const f16* __restrict__ Hh, const f16* __restrict__ Hl,
    const float* __restrict__ W_outT, const float* __restrict__ b_out,
    float* __restrict__ omsg, float* __restrict__ odig,
    float* __restrict__ ologp, int t)
{
    const int lane = threadIdx.x & 63;
    const int wv   = threadIdx.x >> 6;
    const int r0   = blockIdx.x * 8 + wv * 2;

    float a0 = 0.f, a1 = 0.f;
    const f16* hh0 = Hh + (size_t)r0 * HD;
    const f16* hl0 = Hl + (size_t)r0 * HD;
    const f16* hh1 = hh0 + HD;
    const f16* hl1 = hl0 + HD;
    for (int k = 0; k < HD; k += 4) {
        const float w0 = W_outT[(k + 0) * 64 + lane];
        const float w1 = W_outT[(k + 1) * 64 + lane];
        const float w2 = W_outT[(k + 2) * 64 + lane];
        const float w3 = W_outT[(k + 3) * 64 + lane];
        const f16x4 vh0 = *(const f16x4*)&hh0[k];
        const f16x4 vl0 = *(const f16x4*)&hl0[k];
        const f16x4 vh1 = *(const f16x4*)&hh1[k];
        const f16x4 vl1 = *(const f16x4*)&hl1[k];
        a0 += w0 * ((float)vh0[0] + (float)vl0[0]) + w1 * ((float)vh0[1] + (float)vl0[1])
            + w2 * ((float)vh0[2] + (float)vl0[2]) + w3 * ((float)vh0[3] + (float)vl0[3]);
        a1 += w0 * ((float)vh1[0] + (float)vl1[0]) + w1 * ((float)vh1[1] + (float)vl1[1])
            + w2 * ((float)vh1[2] + (float)vl1[2]) + w3 * ((float)vh1[3] + (float)vl1[3]);
    }
    const float bo = b_out[lane];
    const float accs[2] = {a0, a1};

#pragma unroll
    for (int r = 0; r < 2; ++r) {
        const int row = r0 + r;
        const float lg = accs[r] + bo;

        float m = lg; int am = lane;
#pragma unroll
        for (int d = 1; d < 64; d <<= 1) {
            const float om = __shfl_xor(m, d);
            const int   oa = __shfl_xor(am, d);
            if (om > m || (om == m && oa < am)) { m = om; am = oa; }
        }
        float s = expf(lg - m);
#pragma unroll
        for (int d = 1; d < 64; d <<= 1) s += __shfl_xor(s, d);

        odig[(size_t)row * VOC + lane] = lg;
        omsg[(size_t)row * VOC + lane] = (lane == am) ? 1.0f : 0.0f;
        if (lane == 0) {
            const float prev = (t == 0) ? 0.0f : ologp[row];
            ologp[row] = prev - logf(s);
        }
    }
}

// ---------------- XG table: XG[v][j*4+g] = relu(x_v)@W_ih^T + b_ih + b_hh ---
__global__ __launch_bounds__(256) void xg_kernel(
    const float* __restrict__ W_ih, const float* __restrict__ rembT,  // [1024][64]
    const float* __restrict__ rembX0, const float* __restrict__ bR,
    float* __restrict__ XG)                                           // [65][4096]
{
    __shared__ float sW[4][1024];
    const int lane = threadIdx.x & 63;
    const int wv   = threadIdx.x >> 6;
    const int np   = blockIdx.x * 4 + wv;
    const int orig = orig_n(np);
    const float* wr = W_ih + (size_t)orig * HD;
#pragma unroll
    for (int c = 0; c < 4; ++c)
        *(float4*)&sW[wv][c * 256 + lane * 4] = *(const float4*)&wr[c * 256 + lane * 4];
    __syncthreads();

    float acc = 0.f, acc0 = 0.f;
#pragma unroll 4
    for (int k = 0; k < HD; ++k) {
        const float w = sW[wv][k];
        acc  += w * rembT[k * 64 + lane];
        acc0 += w * rembX0[k];
    }
    const float b = bR[np];
    const int g = (np >> 4) & 3;
    const int pos = j_of(np) * 4 + g;
    XG[(size_t)lane * NG + pos] = acc + b;
    if (lane == 0) XG[(size_t)64 * NG + pos] = acc0 + b;
}

// ---------------- merged prep: W split + h split + c copy + small tables ----
__global__ __launch_bounds__(256) void prep_all(
    const float* __restrict__ W_hh, const float* __restrict__ ench,
    const float* __restrict__ encc, const float* __restrict__ W_out,
    const float* __restrict__ b_ih, const float* __restrict__ b_hh,
    const float* __restrict__ emb, const float* __restrict__ x0,
    f16* __restrict__ Whi, f16* __restrict__ Wlo,
    f16* __restrict__ Hh, f16* __restrict__ Hl,
    float* __restrict__ cbuf,
    float* __restrict__ W_outT, f16* __restrict__ Wohi, f16* __restrict__ Wolo,
    float* __restrict__ rembT, float* __restrict__ rembX0,
    float* __restrict__ bR, float* __restrict__ mask)
{
    const int u = blockIdx.x * 256 + threadIdx.x;   // 0 .. 1M-1
    const long long idx = (long long)u * 4;

    // --- W_hh permuted + hi/lo split (NG*KH elements) ---
    {
        const int np = (int)(idx >> 10);
        const int k  = (int)(idx & 1023);
        const float4 v = *(const float4*)&W_hh[(size_t)orig_n(np) * HD + k];
        f16x4 vh, vl; f16 hi_, lo_;
        splt(v.x, hi_, lo_); vh[0] = hi_; vl[0] = lo_;
        splt(v.y, hi_, lo_); vh[1] = hi_; vl[1] = lo_;
        splt(v.z, hi_, lo_); vh[2] = hi_; vl[2] = lo_;
        splt(v.w, hi_, lo_); vh[3] = hi_; vl[3] = lo_;
        *(f16x4*)&Whi[idx] = vh;
        *(f16x4*)&Wlo[idx] = vl;
    }
    // --- encoder_hidden hi/lo split (BATCH*HD elements) ---
    {
        const float4 v = *(const float4*)&ench[idx];
        f16x4 vh, vl; f16 hi_, lo_;
        splt(v.x, hi_, lo_); vh[0] = hi_; vl[0] = lo_;
        splt(v.y, hi_, lo_); vh[1] = hi_; vl[1] = lo_;
        splt(v.z, hi_, lo_); vh[2] = hi_; vl[2] = lo_;
        splt(v.w, hi_, lo_); vh[3] = hi_; vl[3] = lo_;
        *(f16x4*)&Hh[idx] = vh;
        *(f16x4*)&Hl[idx] = vl;
    }
    // --- encoder_cell copy ---
    *(float4*)&cbuf[idx] = *(const float4*)&encc[idx];

    // --- small tables ---
    if (u < 65536) {
        const int i = u;
        mask[i] = 1.0f;
        const int v = i >> 10, k = i & 1023;
        const float wo = W_out[i];
        W_outT[k * 64 + v] = wo;
        f16 hi2, lo2; splt(wo, hi2, lo2);
        Wohi[i] = hi2; Wolo[i] = lo2;               // [64][1024] row-major
        rembT[k * 64 + v] = fmaxf(emb[i], 0.f);
        if (i < 1024) rembX0[i] = fmaxf(x0[i], 0.f);
        if (i < NG) {
            const int orig = orig_n(i);
            bR[i] = b_ih[orig] + b_hh[orig];
        }
    }
}

// ---------------- launch ----------------------------------------------------
extern "C" void kernel_launch(void* const* d_in, const int* in_sizes, int n_in,
                              void* d_out, int out_size, void* d_ws, size_t ws_size,
                              hipStream_t stream)
{
    const float* ench  = (const float*)d_in[0];
    const float* encc  = (const float*)d_in[1];
    const float* W_ih  = (const float*)d_in[2];
    const float* W_hh  = (const float*)d_in[3];
    const float* b_ih  = (const float*)d_in[4];
    const float* b_hh  = (const float*)d_in[5];
    const float* W_out = (const float*)d_in[6];
    const float* b_out = (const float*)d_in[7];
    const float* x0    = (const float*)d_in[8];
    const float* emb   = (const float*)d_in[9];
    float* out = (float*)d_out;

    char* ws = (char*)d_ws;
    f16*   Hh[2]  = { (f16*)(ws + ((size_t) 0 << 20)), (f16*)(ws + ((size_t)16 << 20)) };
    f16*   Hl[2]  = { (f16*)(ws + ((size_t) 8 << 20)), (f16*)(ws + ((size_t)24 << 20)) };
    f16*   Whr    = (f16*)(ws + ((size_t)32 << 20));
    f16*   Wlr    = (f16*)(ws + ((size_t)40 << 20));
    float* cbuf   = (float*)(ws + ((size_t)48 << 20));
    float* W_outT = (float*)(ws + ((size_t)64 << 20));
    float* rembT  = (float*)(ws + ((size_t)65 << 20));
    float* rembX0 = (float*)(ws + ((size_t)66 << 20));
    float* bR     = (float*)(ws + ((size_t)66 << 20) + 8192);
    float* XG     = (float*)(ws + ((size_t)67 << 20));
    f16*   Wohi   = (f16*)(ws + ((size_t)70 << 20));
    f16*   Wolo   = (f16*)(ws + ((size_t)71 << 20));

    float* out_msg0 = out;                                        // [L,B,V]
    float* out_mask = out + (size_t)MSGL * BATCH * VOC;           // [L,1,B]
    float* out_dig0 = out_mask + (size_t)MSGL * BATCH;            // [L,B,V]
    float* out_logp = out_dig0 + (size_t)MSGL * BATCH * VOC;      // [B]

    prep_all<<<4096, 256, 0, stream>>>(
        W_hh, ench, encc, W_out, b_ih, b_hh, emb, x0,
        Whr, Wlr, Hh[0], Hl[0], cbuf,
        W_outT, Wohi, Wolo, rembT, rembX0, bR, out_mask);
    xg_kernel<<<1024, 256, 0, stream>>>(W_ih, rembT, rembX0, bR, XG);

    for (int t = 0; t < MSGL; ++t) {
        const int cur = t & 1, nxt = cur ^ 1;
        gemm_fused<<<dim3(16, 16), 512, 0, stream>>>(
            Hh[cur], Hl[cur], Whr, Wlr, Wohi, Wolo, XG, b_out,
            cbuf, Hh[nxt], Hl[nxt],
            out_msg0, out_dig0, out_logp, t);
    }
    // final step's logits use h_16 (written by gemm t=15 into Hh[0]/Hl[0])
    logits_step<<<512, 256, 0, stream>>>(
        Hh[0], Hl[0], W_outT, b_out,
        out_msg0 + (size_t)(MSGL - 1) * BATCH * VOC,
        out_dig0 + (size_t)(MSGL - 1) * BATCH * VOC,
        out_logp, MSGL - 1);
}